// Round 20
// baseline (172.830 us; speedup 1.0000x reference)
//
#include <hip/hip_runtime.h>
#include <hip/hip_cooperative_groups.h>
#include <hip/hip_bf16.h>
#include <math.h>

#define SEQ 2048
#define NH  16
#define HD  64
#define NW  4   // waves per block (split-KV within block)

typedef __attribute__((ext_vector_type(8)))  short bf16x8;
typedef __attribute__((ext_vector_type(4)))  float f32x4;
typedef __attribute__((ext_vector_type(16))) float f32x16;

static __device__ inline short f2bf(float f) {
  union { float f; unsigned u; } x; x.f = f;
  unsigned u = x.u;
  unsigned r = (u + 0x7fffu + ((u >> 16) & 1u)) >> 16;  // RNE
  return (short)r;
}
static __device__ inline unsigned pack2(float e, float o) {
  union { __hip_bfloat162 h; unsigned u; } c;
  c.h = __float22bfloat162_rn(make_float2(e, o));
  return c.u;
}
static __device__ inline bf16x8 cvt8(float4 a, float4 b) {
  union { __hip_bfloat162 h[4]; bf16x8 v; } u;
  u.h[0] = __float22bfloat162_rn(make_float2(a.x, a.y));
  u.h[1] = __float22bfloat162_rn(make_float2(a.z, a.w));
  u.h[2] = __float22bfloat162_rn(make_float2(b.x, b.y));
  u.h[3] = __float22bfloat162_rn(make_float2(b.z, b.w));
  return u.v;
}

// ---- standalone prepass (fallback path) ---------------------------------------
__global__ __launch_bounds__(256) void conv_kv_kernel(
    const float* __restrict__ K, const float* __restrict__ V,
    short* __restrict__ Kf, short* __restrict__ Vf) {
  __shared__ short tile[64][72];
  const int h = blockIdx.y;
  const int t64 = blockIdx.x;
  const int tid = threadIdx.x;
  const int c = tid >> 6;
  const int lane = tid & 63;
  const int ql = lane & 31;
  const int hi = lane >> 5;

#pragma unroll
  for (int half = 0; half < 2; ++half) {
    const int t32 = t64 * 2 + half;
    const float* src = K + ((size_t)(h * SEQ + t32 * 32 + ql)) * HD + c * 16 + hi * 8;
    float4 a = *(const float4*)src;
    float4 b = *(const float4*)(src + 4);
    *(bf16x8*)(Kf + (((size_t)(h * 64 + t32) * 4 + c) * 64 + lane) * 8) = cvt8(a, b);
  }
  {
    const int r = tid >> 2, c0 = (tid & 3) * 16;
    const float* vs = V + ((size_t)(h * SEQ + t64 * 64 + r)) * HD + c0;
    float4 a0 = *(const float4*)(vs);
    float4 b0 = *(const float4*)(vs + 4);
    float4 a1 = *(const float4*)(vs + 8);
    float4 b1 = *(const float4*)(vs + 12);
    *(bf16x8*)&tile[r][c0]     = cvt8(a0, b0);
    *(bf16x8*)&tile[r][c0 + 8] = cvt8(a1, b1);
  }
  __syncthreads();
#pragma unroll
  for (int dt = 0; dt < 2; ++dt) {
    const int d = dt * 32 + ql;
    bf16x8 o;
#pragma unroll
    for (int j = 0; j < 8; ++j) o[j] = tile[c * 16 + hi * 8 + j][d];
    *(bf16x8*)(Vf + ((((size_t)(h * 32 + t64) * 2 + dt) * 4 + c) * 64 + lane) * 8) = o;
  }
}

// ---- attention phase body (shared by fused and standalone kernels) ------------
// r16 structure (best measured 32.8us): swapped 32x32, no-max softmax, KV-32,
// permlane32_swap PV frags, swizzle v2 (head-local XCD, weight-complementary).
// mfma_f32_32x32x16_bf16: A row=lane&31, k=(lane>>5)*8+i; B col=lane&31, same k;
// C/D col=lane&31, row=(reg&3)+8*(reg>>2)+4*(lane>>5).
static __device__ __forceinline__ void attn_phase(
    const float* __restrict__ Q, const short* __restrict__ Kf,
    const short* __restrict__ Vf, float* __restrict__ Out,
    char* smem, int qt, int h, int w, int lane, int ql, int hi) {
  float (*lds_part)[65] = (float(*)[65])smem;
  float (*lds_l)[2][32] = (float(*)[2][32])(smem + NW * 32 * 65 * 4);

  const int q0 = qt * 32;
  const size_t hqb = (size_t)h * SEQ * HD;

  const float QSCALE = 0.125f * 1.4426950408889634f;  // fold 1/sqrt(D)*log2(e)
  bf16x8 qa[4];
  {
    const float* qbase = Q + hqb + (size_t)(q0 + ql) * HD + 8 * hi;
#pragma unroll
    for (int c = 0; c < 4; ++c) {
      const float* p = qbase + 16 * c;
      float4 a4 = *(const float4*)p;
      float4 b4 = *(const float4*)(p + 4);
      bf16x8 tt;
      tt[0] = f2bf(a4.x * QSCALE); tt[1] = f2bf(a4.y * QSCALE);
      tt[2] = f2bf(a4.z * QSCALE); tt[3] = f2bf(a4.w * QSCALE);
      tt[4] = f2bf(b4.x * QSCALE); tt[5] = f2bf(b4.y * QSCALE);
      tt[6] = f2bf(b4.z * QSCALE); tt[7] = f2bf(b4.w * QSCALE);
      qa[c] = tt;
    }
  }

  f32x16 ot0, ot1;
#pragma unroll
  for (int r = 0; r < 16; ++r) { ot0[r] = 0.f; ot1[r] = 0.f; }
  float ll = 0.f;

  const int n32 = qt + 1;
  for (int t32 = w; t32 < n32; t32 += NW) {
    const short* kbase = Kf + ((size_t)(h * 64 + t32) * 4) * 512 + lane * 8;
    bf16x8 kb[4];
#pragma unroll
    for (int c = 0; c < 4; ++c) kb[c] = *(const bf16x8*)(kbase + c * 512);

    const int t64 = t32 >> 1, ccb = (t32 & 1) * 2;
    const short* vbase = Vf + (((size_t)(h * 32 + t64) * 2) * 4 + ccb) * 512 + lane * 8;
    bf16x8 va0[2], va1[2];
    va0[0] = *(const bf16x8*)(vbase);
    va0[1] = *(const bf16x8*)(vbase + 512);
    va1[0] = *(const bf16x8*)(vbase + 2048);
    va1[1] = *(const bf16x8*)(vbase + 2048 + 512);

    f32x16 st;
#pragma unroll
    for (int r = 0; r < 16; ++r) st[r] = 0.f;
#pragma unroll
    for (int c = 0; c < 4; ++c)
      st = __builtin_amdgcn_mfma_f32_32x32x16_bf16(kb[c], qa[c], st, 0, 0, 0);

    if (t32 == n32 - 1) {
      const int qg = q0 + ql;
#pragma unroll
      for (int r = 0; r < 16; ++r) {
        int kv = t32 * 32 + (r & 3) + 8 * (r >> 2) + 4 * hi;
        if (kv > qg) st[r] = -INFINITY;
      }
    }

    float e[16];
    unsigned pk[8];
#pragma unroll
    for (int mm = 0; mm < 8; ++mm) {
      float a0 = exp2f(st[2 * mm]);
      float a1 = exp2f(st[2 * mm + 1]);
      e[2 * mm] = a0; e[2 * mm + 1] = a1;
      pk[mm] = pack2(a0, a1);
    }
    {
      float s01 = (e[0] + e[1]) + (e[2] + e[3]);
      float s23 = (e[4] + e[5]) + (e[6] + e[7]);
      float s45 = (e[8] + e[9]) + (e[10] + e[11]);
      float s67 = (e[12] + e[13]) + (e[14] + e[15]);
      ll += (s01 + s23) + (s45 + s67);
    }

    {
      union { unsigned u[4]; bf16x8 v; } pb;
      auto r0 = __builtin_amdgcn_permlane32_swap((int)pk[0], (int)pk[2], false, false);
      auto r1 = __builtin_amdgcn_permlane32_swap((int)pk[1], (int)pk[3], false, false);
      pb.u[0] = (unsigned)r0[0]; pb.u[2] = (unsigned)r0[1];
      pb.u[1] = (unsigned)r1[0]; pb.u[3] = (unsigned)r1[1];
      ot0 = __builtin_amdgcn_mfma_f32_32x32x16_bf16(va0[0], pb.v, ot0, 0, 0, 0);
      ot1 = __builtin_amdgcn_mfma_f32_32x32x16_bf16(va1[0], pb.v, ot1, 0, 0, 0);
      auto r2 = __builtin_amdgcn_permlane32_swap((int)pk[4], (int)pk[6], false, false);
      auto r3 = __builtin_amdgcn_permlane32_swap((int)pk[5], (int)pk[7], false, false);
      pb.u[0] = (unsigned)r2[0]; pb.u[2] = (unsigned)r2[1];
      pb.u[1] = (unsigned)r3[0]; pb.u[3] = (unsigned)r3[1];
      ot0 = __builtin_amdgcn_mfma_f32_32x32x16_bf16(va0[1], pb.v, ot0, 0, 0, 0);
      ot1 = __builtin_amdgcn_mfma_f32_32x32x16_bf16(va1[1], pb.v, ot1, 0, 0, 0);
    }
  }

#pragma unroll
  for (int r = 0; r < 16; ++r) {
    lds_part[w * 32 + r][lane] = ot0[r];
    lds_part[w * 32 + 16 + r][lane] = ot1[r];
  }
  lds_l[w][hi][ql] = ll;
  __syncthreads();

  {
    const int q = w * 8 + (lane >> 3);
    const int db = (lane & 7) * 8;
    float lt = 0.f;
#pragma unroll
    for (int wv = 0; wv < NW; ++wv)
      lt += lds_l[wv][0][q] + lds_l[wv][1][q];
    float inv = 1.f / lt;
    float od[8];
#pragma unroll
    for (int j2 = 0; j2 < 8; ++j2) {
      int d = db + j2;
      int tile = d >> 5, dd = d & 31;
      int hid = (dd >> 2) & 1;
      int r = (dd & 3) + 4 * (dd >> 3);
      int row0 = tile * 16 + r;
      int col = q + 32 * hid;
      float acc = 0.f;
#pragma unroll
      for (int wv = 0; wv < NW; ++wv)
        acc += lds_part[wv * 32 + row0][col];
      od[j2] = acc * inv;
    }
    float* outp = Out + hqb + (size_t)(q0 + q) * HD + db;
    *(f32x4*)(outp)     = (f32x4){od[0], od[1], od[2], od[3]};
    *(f32x4*)(outp + 4) = (f32x4){od[4], od[5], od[6], od[7]};
  }
}

// swizzle v2 decode (r16): head-local per XCD + weight-complementary per CU
static __device__ __forceinline__ void decode_swizzle(int id, int& qt, int& h) {
  const int x = id & 7;
  const int j = id >> 3;
  h = 2 * x + (j & 1);
  const int b = j >> 1;
  const int cc = b & 15;
  const int t = b >> 4;
  const int g = cc + ((t >> 1) << 4);
  qt = (t & 1) ? 63 - g : g;
}

#define SMEM_BYTES (NW * 32 * 65 * 4 + NW * 2 * 32 * 4)

// ---- fused cooperative kernel: phase1 convert own tile, grid.sync, attention --
__global__ __launch_bounds__(256, 4) void attn_fused_kernel(
    const float* __restrict__ Q, const float* __restrict__ K,
    const float* __restrict__ V, short* __restrict__ Kf,
    short* __restrict__ Vf, float* __restrict__ Out) {
  const int tid = threadIdx.x;
  const int w = tid >> 6;
  const int lane = tid & 63;
  const int ql = lane & 31;
  const int hi = lane >> 5;

  int qt, h;
  decode_swizzle(blockIdx.x, qt, h);

  __shared__ __align__(16) char smem[SMEM_BYTES];

  // ---- phase 1: convert this block's 1:1 tile (t32 = qt, head h) ----
  {
    const int c = tid >> 6;  // 0..3
    // K tile
    const float* src = K + ((size_t)(h * SEQ + qt * 32 + ql)) * HD + c * 16 + hi * 8;
    float4 a4 = *(const float4*)src;
    float4 b4 = *(const float4*)(src + 4);
    *(bf16x8*)(Kf + (((size_t)(h * 64 + qt) * 4 + c) * 64 + lane) * 8) = cvt8(a4, b4);
    // V tile: stage rows in LDS (aliased onto smem), emit transposed fragments
    short (*tile)[72] = (short(*)[72])smem;  // 32 x 72 bf16 = 4.6 KB
    {
      const int r = tid >> 3;        // 0..31
      const int c0 = (tid & 7) * 8;  // 0..56
      const float* vs = V + ((size_t)(h * SEQ + qt * 32 + r)) * HD + c0;
      float4 va = *(const float4*)vs;
      float4 vb = *(const float4*)(vs + 4);
      *(bf16x8*)&tile[r][c0] = cvt8(va, vb);
    }
    __syncthreads();
    {
      const int t64 = qt >> 1, ccb = (qt & 1) * 2;
      const int cidx = tid >> 7;       // 0..1
      const int dt = (tid >> 6) & 1;   // 0..1
      bf16x8 o;
#pragma unroll
      for (int jj = 0; jj < 8; ++jj)
        o[jj] = tile[cidx * 16 + hi * 8 + jj][dt * 32 + ql];
      *(bf16x8*)(Vf + ((((size_t)(h * 32 + t64) * 2 + dt) * 4 + (ccb + cidx)) * 64 + lane) * 8) = o;
    }
    __threadfence();  // device-scope visibility before the grid barrier
  }
  cooperative_groups::this_grid().sync();

  // ---- phase 2: attention (smem reused as lds_part/lds_l) ----
  attn_phase(Q, Kf, Vf, Out, smem, qt, h, w, lane, ql, hi);
}

// ---- standalone attention kernel (fallback path) ------------------------------
__global__ __launch_bounds__(256, 4) void attn_fwd_kernel(
    const float* __restrict__ Q, const short* __restrict__ Kf,
    const short* __restrict__ Vf, float* __restrict__ Out) {
  const int tid = threadIdx.x;
  const int w = tid >> 6;
  const int lane = tid & 63;
  const int ql = lane & 31;
  const int hi = lane >> 5;
  int qt, h;
  decode_swizzle(blockIdx.x, qt, h);
  __shared__ __align__(16) char smem[SMEM_BYTES];
  attn_phase(Q, Kf, Vf, Out, smem, qt, h, w, lane, ql, hi);
}

// ---------------- fallback (self-contained, f32 inputs) ------------------------
__global__ __launch_bounds__(64) void attn_fwd_fallback(
    const float* __restrict__ Q, const float* __restrict__ K,
    const float* __restrict__ V, float* __restrict__ Out) {
  const int lane = threadIdx.x & 63;
  const int lr = lane & 15;
  const int lg = lane >> 4;
  const int q0 = blockIdx.x * 16;
  const size_t hb = (size_t)blockIdx.y * SEQ * HD;
  const float LOG2E = 1.4426950408889634f;

  bf16x8 qa[2];
  {
    const float* qrow = Q + hb + (size_t)(q0 + lr) * HD;
#pragma unroll
    for (int dh = 0; dh < 2; ++dh) {
      const float* p = qrow + dh * 32 + lg * 8;
      bf16x8 t;
#pragma unroll
      for (int i = 0; i < 8; ++i) t[i] = f2bf(p[i] * 0.125f);
      qa[dh] = t;
    }
  }
  f32x4 o[4];
#pragma unroll
  for (int dt = 0; dt < 4; ++dt) o[dt] = (f32x4){0.f, 0.f, 0.f, 0.f};
  float m[4], ll[4];
#pragma unroll
  for (int r = 0; r < 4; ++r) { m[r] = -INFINITY; ll[r] = 0.f; }
  __shared__ float plds[16][33];
  const int nsteps = (q0 + 16 + 31) >> 5;
  for (int s = 0; s < nsteps; ++s) {
    const int k0 = s * 32;
    bf16x8 kb[2][2];
#pragma unroll
    for (int ct = 0; ct < 2; ++ct) {
      const float* krow = K + hb + (size_t)(k0 + ct * 16 + lr) * HD;
#pragma unroll
      for (int dh = 0; dh < 2; ++dh) {
        const float* p = krow + dh * 32 + lg * 8;
        bf16x8 t;
#pragma unroll
        for (int i = 0; i < 8; ++i) t[i] = f2bf(p[i]);
        kb[ct][dh] = t;
      }
    }
    f32x4 sc[2];
#pragma unroll
    for (int ct = 0; ct < 2; ++ct) {
      f32x4 z = (f32x4){0.f, 0.f, 0.f, 0.f};
      z = __builtin_amdgcn_mfma_f32_16x16x32_bf16(qa[0], kb[ct][0], z, 0, 0, 0);
      z = __builtin_amdgcn_mfma_f32_16x16x32_bf16(qa[1], kb[ct][1], z, 0, 0, 0);
      sc[ct] = z;
    }
    if (s == nsteps - 1) {
#pragma unroll
      for (int ct = 0; ct < 2; ++ct)
#pragma unroll
        for (int r = 0; r < 4; ++r) {
          int col = k0 + ct * 16 + lr;
          int row = q0 + 4 * lg + r;
          if (col > row) sc[ct][r] = -INFINITY;
        }
    }
    float mx[4];
#pragma unroll
    for (int r = 0; r < 4; ++r) mx[r] = fmaxf(sc[0][r], sc[1][r]);
#pragma unroll
    for (int off = 1; off < 16; off <<= 1)
#pragma unroll
      for (int r = 0; r < 4; ++r) mx[r] = fmaxf(mx[r], __shfl_xor(mx[r], off, 64));
    float fac[4], pr[2][4], rs[4];
#pragma unroll
    for (int r = 0; r < 4; ++r) {
      float mn = fmaxf(m[r], mx[r]);
      fac[r] = exp2f((m[r] - mn) * LOG2E);
      m[r] = mn;
      float sum = 0.f;
#pragma unroll
      for (int ct = 0; ct < 2; ++ct) {
        float p = exp2f((sc[ct][r] - mn) * LOG2E);
        pr[ct][r] = p;
        sum += p;
      }
      rs[r] = sum;
    }
#pragma unroll
    for (int off = 1; off < 16; off <<= 1)
#pragma unroll
      for (int r = 0; r < 4; ++r) rs[r] += __shfl_xor(rs[r], off, 64);
#pragma unroll
    for (int r = 0; r < 4; ++r) ll[r] = ll[r] * fac[r] + rs[r];
#pragma unroll
    for (int dt = 0; dt < 4; ++dt)
#pragma unroll
      for (int r = 0; r < 4; ++r) o[dt][r] *= fac[r];
    __syncthreads();
#pragma unroll
    for (int ct = 0; ct < 2; ++ct)
#pragma unroll
      for (int r = 0; r < 4; ++r)
        plds[4 * lg + r][ct * 16 + lr] = pr[ct][r];
    __syncthreads();
    bf16x8 pa;
    {
      const float* p = &plds[lr][lg * 8];
#pragma unroll
      for (int i = 0; i < 8; ++i) pa[i] = f2bf(p[i]);
    }
#pragma unroll
    for (int dt = 0; dt < 4; ++dt) {
      const float* vcol = V + hb + (size_t)(k0 + lg * 8) * HD + dt * 16 + lr;
      bf16x8 vb;
#pragma unroll
      for (int i = 0; i < 8; ++i) vb[i] = f2bf(vcol[(size_t)i * HD]);
      o[dt] = __builtin_amdgcn_mfma_f32_16x16x32_bf16(pa, vb, o[dt], 0, 0, 0);
    }
  }
#pragma unroll
  for (int dt = 0; dt < 4; ++dt)
#pragma unroll
    for (int r = 0; r < 4; ++r) {
      int row = q0 + 4 * lg + r;
      Out[hb + (size_t)row * HD + dt * 16 + lr] = o[dt][r] / ll[r];
    }
}

extern "C" void kernel_launch(void* const* d_in, const int* in_sizes, int n_in,
                              void* d_out, int out_size, void* d_ws, size_t ws_size,
                              hipStream_t stream) {
  const float* q = (const float*)d_in[0];
  const float* k = (const float*)d_in[1];
  const float* v = (const float*)d_in[2];
  float* out = (float*)d_out;

  const size_t elems = (size_t)NH * SEQ * HD;      // 2,097,152
  const size_t need = 2 * elems * sizeof(short);   // 8 MB

  if (ws_size >= need) {
    short* Kf = (short*)d_ws;
    short* Vf = Kf + elems;

    int coop = 0;
    hipDeviceGetAttribute(&coop, hipDeviceAttributeCooperativeLaunch, 0);
    bool done = false;
    if (coop) {
      void* args[] = {(void*)&q, (void*)&k, (void*)&v,
                      (void*)&Kf, (void*)&Vf, (void*)&out};
      hipError_t e = hipLaunchCooperativeKernel(
          (const void*)attn_fused_kernel, dim3((SEQ / 32) * NH), dim3(256),
          args, 0, stream);
      done = (e == hipSuccess);
    }
    if (!done) {
      conv_kv_kernel<<<dim3(SEQ / 64, NH), 256, 0, stream>>>(k, v, Kf, Vf);
      attn_fwd_kernel<<<dim3((SEQ / 32) * NH), 256, 0, stream>>>(q, Kf, Vf, out);
    }
  } else {
    attn_fwd_fallback<<<dim3(SEQ / 16, NH), dim3(64), 0, stream>>>(q, k, v, out);
  }
}

// Round 21
// 32.603 us; speedup vs baseline: 5.3011x; 5.3011x over previous
//
#include <hip/hip_runtime.h>
#include <hip/hip_bf16.h>
#include <math.h>

#define SEQ 2048
#define NH  16
#define HD  64
#define NW  4   // waves per block (split-KV within block)

typedef __attribute__((ext_vector_type(8)))  short bf16x8;
typedef __attribute__((ext_vector_type(4)))  float f32x4;
typedef __attribute__((ext_vector_type(16))) float f32x16;

static __device__ inline short f2bf(float f) {
  union { float f; unsigned u; } x; x.f = f;
  unsigned u = x.u;
  unsigned r = (u + 0x7fffu + ((u >> 16) & 1u)) >> 16;  // RNE
  return (short)r;
}
// native packed f32x2 -> bf16x2 (v_cvt_pk_bf16_f32); lo = e
static __device__ inline unsigned pack2(float e, float o) {
  union { __hip_bfloat162 h; unsigned u; } c;
  c.h = __float22bfloat162_rn(make_float2(e, o));
  return c.u;
}
static __device__ inline bf16x8 cvt8(float4 a, float4 b) {
  union { __hip_bfloat162 h[4]; bf16x8 v; } u;
  u.h[0] = __float22bfloat162_rn(make_float2(a.x, a.y));
  u.h[1] = __float22bfloat162_rn(make_float2(a.z, a.w));
  u.h[2] = __float22bfloat162_rn(make_float2(b.x, b.y));
  u.h[3] = __float22bfloat162_rn(make_float2(b.z, b.w));
  return u.v;
}

// ---- prepass: emit K and V in MFMA-fragment order (lane-major, coalesced) -----
__global__ __launch_bounds__(256) void conv_kv_kernel(
    const float* __restrict__ K, const float* __restrict__ V,
    short* __restrict__ Kf, short* __restrict__ Vf) {
  __shared__ short tile[64][72];
  const int h = blockIdx.y;
  const int t64 = blockIdx.x;
  const int tid = threadIdx.x;
  const int c = tid >> 6;
  const int lane = tid & 63;
  const int ql = lane & 31;
  const int hi = lane >> 5;

#pragma unroll
  for (int half = 0; half < 2; ++half) {
    const int t32 = t64 * 2 + half;
    const float* src = K + ((size_t)(h * SEQ + t32 * 32 + ql)) * HD + c * 16 + hi * 8;
    float4 a = *(const float4*)src;
    float4 b = *(const float4*)(src + 4);
    *(bf16x8*)(Kf + (((size_t)(h * 64 + t32) * 4 + c) * 64 + lane) * 8) = cvt8(a, b);
  }
  {
    const int r = tid >> 2, c0 = (tid & 3) * 16;
    const float* vs = V + ((size_t)(h * SEQ + t64 * 64 + r)) * HD + c0;
    float4 a0 = *(const float4*)(vs);
    float4 b0 = *(const float4*)(vs + 4);
    float4 a1 = *(const float4*)(vs + 8);
    float4 b1 = *(const float4*)(vs + 12);
    *(bf16x8*)&tile[r][c0]     = cvt8(a0, b0);
    *(bf16x8*)&tile[r][c0 + 8] = cvt8(a1, b1);
  }
  __syncthreads();
#pragma unroll
  for (int dt = 0; dt < 2; ++dt) {
    const int d = dt * 32 + ql;
    bf16x8 o;
#pragma unroll
    for (int j = 0; j < 8; ++j) o[j] = tile[c * 16 + hi * 8 + j][d];
    *(bf16x8*)(Vf + ((((size_t)(h * 32 + t64) * 2 + dt) * 4 + c) * 64 + lane) * 8) = o;
  }
}

// ---- main: swapped 32x32 flash attention, no-max softmax, KV-32 steps ----------
// r21 = exact r16 restore (best measured: 32.8us). r20's cooperative fusion
// regressed 5x: grid.sync() costs ~140us at 1024 blocks on gfx950 — never trade
// a ~2us kernel gap for a grid-wide barrier.
// Swizzle v2: h = 2*(id&7) + (j&1) -> per-XCD 2 heads (1 MB KV in L2),
// per-CU qts {g, 63-g, g+16, 47-g} -> exactly 130 tile-steps/CU.
// mfma_f32_32x32x16_bf16: A row=lane&31, k=(lane>>5)*8+i; B col=lane&31, same k;
// C/D col=lane&31, row=(reg&3)+8*(reg>>2)+4*(lane>>5).
__global__ __launch_bounds__(256, 4) void attn_fwd_kernel(
    const float* __restrict__ Q, const short* __restrict__ Kf,
    const short* __restrict__ Vf, float* __restrict__ Out) {
  const int tid = threadIdx.x;
  const int w = tid >> 6;        // wave 0..3
  const int lane = tid & 63;
  const int ql = lane & 31;      // q-row owned by this lane
  const int hi = lane >> 5;

  // swizzle v2: id -> (qt, h)
  const int id = blockIdx.x;
  const int x = id & 7;
  const int j = id >> 3;
  const int h = 2 * x + (j & 1);
  const int b = j >> 1;
  const int cc = b & 15;
  const int t = b >> 4;
  const int g = cc + ((t >> 1) << 4);
  const int qt = (t & 1) ? 63 - g : g;

  const int q0 = qt * 32;
  const size_t hqb = (size_t)h * SEQ * HD;

  __shared__ float lds_part[NW * 32][65];
  __shared__ float lds_l[NW][2][32];

  const float QSCALE = 0.125f * 1.4426950408889634f;  // fold 1/sqrt(D) * log2(e)
  bf16x8 qa[4];
  {
    const float* qbase = Q + hqb + (size_t)(q0 + ql) * HD + 8 * hi;
#pragma unroll
    for (int c = 0; c < 4; ++c) {
      const float* p = qbase + 16 * c;
      float4 a4 = *(const float4*)p;
      float4 b4 = *(const float4*)(p + 4);
      bf16x8 tt;
      tt[0] = f2bf(a4.x * QSCALE); tt[1] = f2bf(a4.y * QSCALE);
      tt[2] = f2bf(a4.z * QSCALE); tt[3] = f2bf(a4.w * QSCALE);
      tt[4] = f2bf(b4.x * QSCALE); tt[5] = f2bf(b4.y * QSCALE);
      tt[6] = f2bf(b4.z * QSCALE); tt[7] = f2bf(b4.w * QSCALE);
      qa[c] = tt;
    }
  }

  f32x16 ot0, ot1;   // O^T acc (unnormalized; no-max softmax => no rescale)
#pragma unroll
  for (int r = 0; r < 16; ++r) { ot0[r] = 0.f; ot1[r] = 0.f; }
  float ll = 0.f;

  const int n32 = qt + 1;   // causal KV tiles of 32
  for (int t32 = w; t32 < n32; t32 += NW) {
    // K fragments (one 32-kv tile), V fragments issued early (hide under QK)
    const short* kbase = Kf + ((size_t)(h * 64 + t32) * 4) * 512 + lane * 8;
    bf16x8 kb[4];
#pragma unroll
    for (int c = 0; c < 4; ++c) kb[c] = *(const bf16x8*)(kbase + c * 512);

    const int t64 = t32 >> 1, ccb = (t32 & 1) * 2;
    const short* vbase = Vf + (((size_t)(h * 32 + t64) * 2) * 4 + ccb) * 512 + lane * 8;
    bf16x8 va0[2], va1[2];
    va0[0] = *(const bf16x8*)(vbase);
    va0[1] = *(const bf16x8*)(vbase + 512);
    va1[0] = *(const bf16x8*)(vbase + 2048);
    va1[1] = *(const bf16x8*)(vbase + 2048 + 512);

    // S^T = K . Q  (K=64 over D in 4 chains)
    f32x16 st;
#pragma unroll
    for (int r = 0; r < 16; ++r) st[r] = 0.f;
#pragma unroll
    for (int c = 0; c < 4; ++c)
      st = __builtin_amdgcn_mfma_f32_32x32x16_bf16(kb[c], qa[c], st, 0, 0, 0);

    // causal mask (diagonal tile only)
    if (t32 == n32 - 1) {
      const int qg = q0 + ql;
#pragma unroll
      for (int r = 0; r < 16; ++r) {
        int kv = t32 * 32 + (r & 3) + 8 * (r >> 2) + 4 * hi;
        if (kv > qg) st[r] = -INFINITY;
      }
    }

    // exp2 directly (no max subtraction), sum + pack fused
    float rs = 0.f;
    unsigned pk[8];
#pragma unroll
    for (int mm = 0; mm < 8; ++mm) {
      float a0 = exp2f(st[2 * mm]);
      float a1 = exp2f(st[2 * mm + 1]);
      rs += a0 + a1;
      pk[mm] = pack2(a0, a1);
    }
    ll += rs;   // own-half partial row-sum; hi halves merged in epilogue

    // PV B-frags via permlane32_swap (verified r13 mapping)
    {
      union { unsigned u[4]; bf16x8 v; } pb;
      auto r0 = __builtin_amdgcn_permlane32_swap((int)pk[0], (int)pk[2], false, false);
      auto r1 = __builtin_amdgcn_permlane32_swap((int)pk[1], (int)pk[3], false, false);
      pb.u[0] = (unsigned)r0[0]; pb.u[2] = (unsigned)r0[1];
      pb.u[1] = (unsigned)r1[0]; pb.u[3] = (unsigned)r1[1];
      ot0 = __builtin_amdgcn_mfma_f32_32x32x16_bf16(va0[0], pb.v, ot0, 0, 0, 0);
      ot1 = __builtin_amdgcn_mfma_f32_32x32x16_bf16(va1[0], pb.v, ot1, 0, 0, 0);
      auto r2 = __builtin_amdgcn_permlane32_swap((int)pk[4], (int)pk[6], false, false);
      auto r3 = __builtin_amdgcn_permlane32_swap((int)pk[5], (int)pk[7], false, false);
      pb.u[0] = (unsigned)r2[0]; pb.u[2] = (unsigned)r2[1];
      pb.u[1] = (unsigned)r3[0]; pb.u[3] = (unsigned)r3[1];
      ot0 = __builtin_amdgcn_mfma_f32_32x32x16_bf16(va0[1], pb.v, ot0, 0, 0, 0);
      ot1 = __builtin_amdgcn_mfma_f32_32x32x16_bf16(va1[1], pb.v, ot1, 0, 0, 0);
    }
  }

  // ---- combine: plain sums across waves and hi-halves, then normalize --------
#pragma unroll
  for (int r = 0; r < 16; ++r) {
    lds_part[w * 32 + r][lane] = ot0[r];
    lds_part[w * 32 + 16 + r][lane] = ot1[r];
  }
  lds_l[w][hi][ql] = ll;
  __syncthreads();

  {
    const int q = w * 8 + (lane >> 3);
    const int db = (lane & 7) * 8;
    float lt = 0.f;
#pragma unroll
    for (int wv = 0; wv < NW; ++wv)
      lt += lds_l[wv][0][q] + lds_l[wv][1][q];
    float inv = 1.f / lt;
    float od[8];
#pragma unroll
    for (int j2 = 0; j2 < 8; ++j2) {
      int d = db + j2;
      int tile = d >> 5, dd = d & 31;
      int hid = (dd >> 2) & 1;
      int r = (dd & 3) + 4 * (dd >> 3);
      int row0 = tile * 16 + r;
      int col = q + 32 * hid;
      float acc = 0.f;
#pragma unroll
      for (int wv = 0; wv < NW; ++wv)
        acc += lds_part[wv * 32 + row0][col];
      od[j2] = acc * inv;
    }
    float* outp = Out + hqb + (size_t)(q0 + q) * HD + db;
    *(f32x4*)(outp)     = (f32x4){od[0], od[1], od[2], od[3]};
    *(f32x4*)(outp + 4) = (f32x4){od[4], od[5], od[6], od[7]};
  }
}

// ---------------- fallback (self-contained, f32 inputs) ------------------------
__global__ __launch_bounds__(64) void attn_fwd_fallback(
    const float* __restrict__ Q, const float* __restrict__ K,
    const float* __restrict__ V, float* __restrict__ Out) {
  const int lane = threadIdx.x & 63;
  const int lr = lane & 15;
  const int lg = lane >> 4;
  const int q0 = blockIdx.x * 16;
  const size_t hb = (size_t)blockIdx.y * SEQ * HD;
  const float LOG2E = 1.4426950408889634f;

  bf16x8 qa[2];
  {
    const float* qrow = Q + hb + (size_t)(q0 + lr) * HD;
#pragma unroll
    for (int dh = 0; dh < 2; ++dh) {
      const float* p = qrow + dh * 32 + lg * 8;
      bf16x8 t;
#pragma unroll
      for (int i = 0; i < 8; ++i) t[i] = f2bf(p[i] * 0.125f);
      qa[dh] = t;
    }
  }
  f32x4 o[4];
#pragma unroll
  for (int dt = 0; dt < 4; ++dt) o[dt] = (f32x4){0.f, 0.f, 0.f, 0.f};
  float m[4], ll[4];
#pragma unroll
  for (int r = 0; r < 4; ++r) { m[r] = -INFINITY; ll[r] = 0.f; }
  __shared__ float plds[16][33];
  const int nsteps = (q0 + 16 + 31) >> 5;
  for (int s = 0; s < nsteps; ++s) {
    const int k0 = s * 32;
    bf16x8 kb[2][2];
#pragma unroll
    for (int ct = 0; ct < 2; ++ct) {
      const float* krow = K + hb + (size_t)(k0 + ct * 16 + lr) * HD;
#pragma unroll
      for (int dh = 0; dh < 2; ++dh) {
        const float* p = krow + dh * 32 + lg * 8;
        bf16x8 t;
#pragma unroll
        for (int i = 0; i < 8; ++i) t[i] = f2bf(p[i]);
        kb[ct][dh] = t;
      }
    }
    f32x4 sc[2];
#pragma unroll
    for (int ct = 0; ct < 2; ++ct) {
      f32x4 z = (f32x4){0.f, 0.f, 0.f, 0.f};
      z = __builtin_amdgcn_mfma_f32_16x16x32_bf16(qa[0], kb[ct][0], z, 0, 0, 0);
      z = __builtin_amdgcn_mfma_f32_16x16x32_bf16(qa[1], kb[ct][1], z, 0, 0, 0);
      sc[ct] = z;
    }
    if (s == nsteps - 1) {
#pragma unroll
      for (int ct = 0; ct < 2; ++ct)
#pragma unroll
        for (int r = 0; r < 4; ++r) {
          int col = k0 + ct * 16 + lr;
          int row = q0 + 4 * lg + r;
          if (col > row) sc[ct][r] = -INFINITY;
        }
    }
    float mx[4];
#pragma unroll
    for (int r = 0; r < 4; ++r) mx[r] = fmaxf(sc[0][r], sc[1][r]);
#pragma unroll
    for (int off = 1; off < 16; off <<= 1)
#pragma unroll
      for (int r = 0; r < 4; ++r) mx[r] = fmaxf(mx[r], __shfl_xor(mx[r], off, 64));
    float fac[4], pr[2][4], rs[4];
#pragma unroll
    for (int r = 0; r < 4; ++r) {
      float mn = fmaxf(m[r], mx[r]);
      fac[r] = exp2f((m[r] - mn) * LOG2E);
      m[r] = mn;
      float sum = 0.f;
#pragma unroll
      for (int ct = 0; ct < 2; ++ct) {
        float p = exp2f((sc[ct][r] - mn) * LOG2E);
        pr[ct][r] = p;
        sum += p;
      }
      rs[r] = sum;
    }
#pragma unroll
    for (int off = 1; off < 16; off <<= 1)
#pragma unroll
      for (int r = 0; r < 4; ++r) rs[r] += __shfl_xor(rs[r], off, 64);
#pragma unroll
    for (int r = 0; r < 4; ++r) ll[r] = ll[r] * fac[r] + rs[r];
#pragma unroll
    for (int dt = 0; dt < 4; ++dt)
#pragma unroll
      for (int r = 0; r < 4; ++r) o[dt][r] *= fac[r];
    __syncthreads();
#pragma unroll
    for (int ct = 0; ct < 2; ++ct)
#pragma unroll
      for (int r = 0; r < 4; ++r)
        plds[4 * lg + r][ct * 16 + lr] = pr[ct][r];
    __syncthreads();
    bf16x8 pa;
    {
      const float* p = &plds[lr][lg * 8];
#pragma unroll
      for (int i = 0; i < 8; ++i) pa[i] = f2bf(p[i]);
    }
#pragma unroll
    for (int dt = 0; dt < 4; ++dt) {
      const float* vcol = V + hb + (size_t)(k0 + lg * 8) * HD + dt * 16 + lr;
      bf16x8 vb;
#pragma unroll
      for (int i = 0; i < 8; ++i) vb[i] = f2bf(vcol[(size_t)i * HD]);
      o[dt] = __builtin_amdgcn_mfma_f32_16x16x32_bf16(pa, vb, o[dt], 0, 0, 0);
    }
  }
#pragma unroll
  for (int dt = 0; dt < 4; ++dt)
#pragma unroll
    for (int r = 0; r < 4; ++r) {
      int row = q0 + 4 * lg + r;
      Out[hb + (size_t)row * HD + dt * 16 + lr] = o[dt][r] / ll[r];
    }
}

extern "C" void kernel_launch(void* const* d_in, const int* in_sizes, int n_in,
                              void* d_out, int out_size, void* d_ws, size_t ws_size,
                              hipStream_t stream) {
  const float* q = (const float*)d_in[0];
  const float* k = (const float*)d_in[1];
  const float* v = (const float*)d_in[2];
  float* out = (float*)d_out;

  const size_t elems = (size_t)NH * SEQ * HD;      // 2,097,152
  const size_t need = 2 * elems * sizeof(short);   // 8 MB

  if (ws_size >= need) {
    short* Kf = (short*)d_ws;
    short* Vf = Kf + elems;
    conv_kv_kernel<<<dim3(SEQ / 64, NH), 256, 0, stream>>>(k, v, Kf, Vf);
    attn_fwd_kernel<<<dim3((SEQ / 32) * NH), 256, 0, stream>>>(q, Kf, Vf, out);
  } else {
    attn_fwd_fallback<<<dim3(SEQ / 16, NH), dim3(64), 0, stream>>>(q, k, v, out);
  }
}